// Round 20
// baseline (124.690 us; speedup 1.0000x reference)
//
#include <hip/hip_runtime.h>
#include <hip/hip_bf16.h>

#define T_ 1024
#define N_ 8
#define D_ 1024
#define H_ 16
#define HD_ 64

typedef __attribute__((ext_vector_type(8))) short bf16x8;
typedef __attribute__((ext_vector_type(2))) float f32x2;
typedef __attribute__((ext_vector_type(4))) float f32x4;
typedef __attribute__((ext_vector_type(16))) float f32x16;
typedef __attribute__((ext_vector_type(4))) int i32x4;
typedef __attribute__((ext_vector_type(2))) int i32x2;
typedef unsigned short u16;
typedef unsigned int u32;

__device__ __forceinline__ float bf2f(u16 u){
  union { float f; unsigned int i; } v; v.i = ((unsigned int)u) << 16; return v.f;
}
__device__ __forceinline__ u16 f2bf(float f){
  union { float f; unsigned int i; } v; v.f = f;
  unsigned int r = v.i + 0x7FFFu + ((v.i >> 16) & 1u);
  return (u16)(r >> 16);
}
__device__ __forceinline__ u16 f2bf_fast(float f){
  __hip_bfloat16 h = __float2bfloat16(f);   // RNE; compiler packs pairs into v_cvt_pk_bf16_f32
  return *reinterpret_cast<u16*>(&h);
}
// raw v_exp_f32: args are well inside normal range (p<=e^15), skip libm fixup tail
__device__ __forceinline__ float exp2_raw(float x){
  float r;
  asm("v_exp_f32 %0, %1" : "=v"(r) : "v"(x));
  return r;
}
// async global->LDS, 16B per lane, dest = wave-uniform base + lane*16
__device__ __forceinline__ void gl_lds16(const u16* g, u16* l){
  __builtin_amdgcn_global_load_lds(
      (const __attribute__((address_space(1))) unsigned int*)g,
      (__attribute__((address_space(3))) unsigned int*)(unsigned int)(unsigned long long)l,
      16, 0, 0);
}

// ---------------- fused pre-kernel: blocks 0-255 = bmatp (split-K 16); 256-511 = wqt ----------------
__global__ __launch_bounds__(256) void k_pre(const float* __restrict__ qw, const float* __restrict__ vw,
                                             float* __restrict__ Bp, const float* __restrict__ Wq,
                                             u16* __restrict__ Wqt){
  __shared__ u16 Qt[64 * 72];
  __shared__ u16 Vt[64 * 72];
  __shared__ float tld[64][65];
  int blk = (int)blockIdx.x;
  int tid = threadIdx.x;
  if (blk < 256){
    int h = blk >> 4, sp = blk & 15;
    int lane = tid & 63, w = tid >> 6;
    int g = lane >> 4, c = lane & 15;
    f32x4 zero = {0.f, 0.f, 0.f, 0.f};
    f32x4 acc[4];
    #pragma unroll
    for (int eb = 0; eb < 4; ++eb) acc[eb] = zero;
    int m = tid >> 2, cg = tid & 3;
    int mt = sp * 64;
    #pragma unroll
    for (int q = 0; q < 4; ++q){
      int e0 = cg * 16 + q * 4;
      f32x4 vq = *(const f32x4*)(qw + (size_t)(mt + m) * D_ + h * 64 + e0);
      f32x4 vv = *(const f32x4*)(vw + (size_t)(mt + m) * D_ + h * 64 + e0);
      #pragma unroll
      for (int j = 0; j < 4; ++j){
        Qt[(e0 + j) * 72 + m] = f2bf_fast(vq[j]);
        Vt[(e0 + j) * 72 + m] = f2bf_fast(vv[j]);
      }
    }
    __syncthreads();
    #pragma unroll
    for (int kk = 0; kk < 2; ++kk){
      bf16x8 av = *(const bf16x8*)&Vt[(w * 16 + c) * 72 + kk * 32 + g * 8];
      #pragma unroll
      for (int eb = 0; eb < 4; ++eb){
        bf16x8 bq = *(const bf16x8*)&Qt[(eb * 16 + c) * 72 + kk * 32 + g * 8];
        acc[eb] = __builtin_amdgcn_mfma_f32_16x16x32_bf16(av, bq, acc[eb], 0, 0, 0);
      }
    }
    #pragma unroll
    for (int eb = 0; eb < 4; ++eb)
      #pragma unroll
      for (int r = 0; r < 4; ++r){
        int d = w * 16 + g * 4 + r, e = eb * 16 + c;
        Bp[(((size_t)sp * 16 + h) * 64 + d) * 64 + e] = acc[eb][r];
      }
  } else {
    int b2 = blk - 256;
    int m0 = (b2 & 15) * 64, n0 = (b2 >> 4) * 64;
    int col = tid & 63, rq = tid >> 6;
    #pragma unroll
    for (int p = 0; p < 16; ++p){
      int row = rq * 16 + p;
      tld[row][col] = Wq[(size_t)(m0 + row) * D_ + n0 + col];
    }
    __syncthreads();
    #pragma unroll
    for (int p = 0; p < 16; ++p){
      int row = rq * 16 + p;
      Wqt[(size_t)(n0 + row) * D_ + m0 + col] = f2bf(tld[col][row]);
    }
  }
}

// swizzled u16-index within a [rows][64] u16 LDS tile: XOR byte-bits 4-6 with row&7
__device__ __forceinline__ int swz(int row, int colbyte){
  return row * 64 + (((colbyte) ^ ((row & 7) << 4)) >> 1);
}

// ---------------- 128x128 bf16 MFMA GEMM, A[MxK] @ B^T (B given [N][K]) ----------------
// Double-buffered; bf16 operand via global_load_lds (linear dest, pre-swizzled src);
// f32 operand via T14 split (reg loads early, ds_write after compute).
// EPI=0: scatter to qb bf16 + fused qsq epilogue + tail blocks (>=512) reduce Bp->Bt.
// EPI=1: C f32 + bias.
template<int A_F32, int B_F32, int EPI>
__global__ __launch_bounds__(256) void k_gemm(const void* __restrict__ A_, const void* __restrict__ B_,
                                              void* __restrict__ Cv, const float* __restrict__ bias,
                                              int M, int N, int K,
                                              const float* __restrict__ Bp, u16* __restrict__ Bt,
                                              float* __restrict__ qsq){
  int ii = (int)blockIdx.x;
  if (EPI == 0 && ii >= 512){
    // ---- fused bred: 16 blocks x 256 thr x 16 elems = 65536 (Bp/Bt both in ws)
    int base = (ii - 512) * 4096 + threadIdx.x * 16;
    #pragma unroll 4
    for (int e = 0; e < 16; ++e){
      int idx = base + e;
      float s = 0.f;
      #pragma unroll
      for (int j = 0; j < 16; ++j) s += Bp[(size_t)j * 65536 + idx];
      Bt[idx] = f2bf(s * 0.125f);
    }
    return;
  }
  int nbn = N >> 7;
  int sw = (ii & 7) * 64 + (ii >> 3);      // XCD-contiguous chunks (512 = 8*64 blocks)
  int bm = sw / nbn, bn = sw % nbn;
  int tid = threadIdx.x, lane = tid & 63, wid = tid >> 6;
  int wr = wid >> 1, wc = wid & 1, g = lane >> 4, c = lane & 15;
  __shared__ u16 As[2][128 * 64];
  __shared__ u16 Bs[2][128 * 64];
  int srow[4], scol[4], sdst[4];
  #pragma unroll
  for (int p = 0; p < 4; ++p){
    int slot = (wid * 4 + p) * 64 + lane;
    int row = slot >> 3, c8 = slot & 7;
    srow[p] = row;
    scol[p] = (c8 ^ (row & 7)) * 8;   // pre-swizzled source chunk
    sdst[p] = slot * 8;               // linear dest
  }
  int rrow[4], rc8[4];
  #pragma unroll
  for (int p = 0; p < 4; ++p){
    int ci = tid + p * 256;
    rrow[p] = ci >> 3; rc8[p] = ci & 7;
  }
  f32x4 zero = {0.f, 0.f, 0.f, 0.f};
  f32x4 acc[4][4];
  #pragma unroll
  for (int m = 0; m < 4; ++m)
    #pragma unroll
    for (int n = 0; n < 4; ++n) acc[m][n] = zero;
  f32x4 rA[4][2], rB[4][2];
  const u16* Ab = (const u16*)A_;
  const u16* Bb = (const u16*)B_;
  const float* Af = (const float*)A_;
  const float* Bf = (const float*)B_;
  // ---- prologue: stage tile 0 into buf 0
  if (!A_F32){
    #pragma unroll
    for (int p = 0; p < 4; ++p)
      gl_lds16(Ab + (size_t)(bm * 128 + srow[p]) * K + scol[p], &As[0][sdst[p]]);
  }
  if (!B_F32){
    #pragma unroll
    for (int p = 0; p < 4; ++p)
      gl_lds16(Bb + (size_t)(bn * 128 + srow[p]) * K + scol[p], &Bs[0][sdst[p]]);
  }
  if (A_F32){
    #pragma unroll
    for (int p = 0; p < 4; ++p){
      const float* src = Af + (size_t)(bm * 128 + rrow[p]) * K + rc8[p] * 8;
      rA[p][0] = *(const f32x4*)src;
      rA[p][1] = *(const f32x4*)(src + 4);
    }
    #pragma unroll
    for (int p = 0; p < 4; ++p){
      union { u16 u[8]; i32x4 v; } pk;
      #pragma unroll
      for (int j = 0; j < 4; ++j){ pk.u[j] = f2bf_fast(rA[p][0][j]); pk.u[4 + j] = f2bf_fast(rA[p][1][j]); }
      *(i32x4*)&As[0][swz(rrow[p], rc8[p] * 16)] = pk.v;
    }
  }
  if (B_F32){
    #pragma unroll
    for (int p = 0; p < 4; ++p){
      const float* src = Bf + (size_t)(bn * 128 + rrow[p]) * K + rc8[p] * 8;
      rB[p][0] = *(const f32x4*)src;
      rB[p][1] = *(const f32x4*)(src + 4);
    }
    #pragma unroll
    for (int p = 0; p < 4; ++p){
      union { u16 u[8]; i32x4 v; } pk;
      #pragma unroll
      for (int j = 0; j < 4; ++j){ pk.u[j] = f2bf_fast(rB[p][0][j]); pk.u[4 + j] = f2bf_fast(rB[p][1][j]); }
      *(i32x4*)&Bs[0][swz(rrow[p], rc8[p] * 16)] = pk.v;
    }
  }
  int NT = K >> 6;
  int cur = 0;
  for (int st = 0; st < NT; ++st){
    __syncthreads();   // buf[cur] ready; prev reads of buf[cur^1] done
    int kt1 = (st + 1) * 64;
    int nb = cur ^ 1;
    if (st + 1 < NT){
      if (!A_F32){
        #pragma unroll
        for (int p = 0; p < 4; ++p)
          gl_lds16(Ab + (size_t)(bm * 128 + srow[p]) * K + kt1 + scol[p], &As[nb][sdst[p]]);
      }
      if (!B_F32){
        #pragma unroll
        for (int p = 0; p < 4; ++p)
          gl_lds16(Bb + (size_t)(bn * 128 + srow[p]) * K + kt1 + scol[p], &Bs[nb][sdst[p]]);
      }
      if (A_F32){
        #pragma unroll
        for (int p = 0; p < 4; ++p){
          const float* src = Af + (size_t)(bm * 128 + rrow[p]) * K + kt1 + rc8[p] * 8;
          rA[p][0] = *(const f32x4*)src;
          rA[p][1] = *(const f32x4*)(src + 4);
        }
      }
      if (B_F32){
        #pragma unroll
        for (int p = 0; p < 4; ++p){
          const float* src = Bf + (size_t)(bn * 128 + rrow[p]) * K + kt1 + rc8[p] * 8;
          rB[p][0] = *(const f32x4*)src;
          rB[p][1] = *(const f32x4*)(src + 4);
        }
      }
    }
    // ---- compute on buf[cur]
    #pragma unroll
    for (int kk = 0; kk < 2; ++kk){
      bf16x8 af[4], bfr[4];
      #pragma unroll
      for (int m = 0; m < 4; ++m){
        int row = wr * 64 + m * 16 + c;
        af[m] = *(const bf16x8*)&As[cur][swz(row, kk * 64 + g * 16)];
      }
      #pragma unroll
      for (int n = 0; n < 4; ++n){
        int row = wc * 64 + n * 16 + c;
        bfr[n] = *(const bf16x8*)&Bs[cur][swz(row, kk * 64 + g * 16)];
      }
      #pragma unroll
      for (int m = 0; m < 4; ++m)
        #pragma unroll
        for (int n = 0; n < 4; ++n)
          acc[m][n] = __builtin_amdgcn_mfma_f32_16x16x32_bf16(af[m], bfr[n], acc[m][n], 0, 0, 0);
    }
    // ---- late ds_write of the f32-path tile
    if (st + 1 < NT){
      if (A_F32){
        #pragma unroll
        for (int p = 0; p < 4; ++p){
          union { u16 u[8]; i32x4 v; } pk;
          #pragma unroll
          for (int j = 0; j < 4; ++j){ pk.u[j] = f2bf_fast(rA[p][0][j]); pk.u[4 + j] = f2bf_fast(rA[p][1][j]); }
          *(i32x4*)&As[nb][swz(rrow[p], rc8[p] * 16)] = pk.v;
        }
      }
      if (B_F32){
        #pragma unroll
        for (int p = 0; p < 4; ++p){
          union { u16 u[8]; i32x4 v; } pk;
          #pragma unroll
          for (int j = 0; j < 4; ++j){ pk.u[j] = f2bf_fast(rB[p][0][j]); pk.u[4 + j] = f2bf_fast(rB[p][1][j]); }
          *(i32x4*)&Bs[nb][swz(rrow[p], rc8[p] * 16)] = pk.v;
        }
      }
    }
    cur ^= 1;
  }
  #pragma unroll
  for (int m = 0; m < 4; ++m)
    #pragma unroll
    for (int n = 0; n < 4; ++n)
      #pragma unroll
      for (int r = 0; r < 4; ++r){
        int row = bm * 128 + wr * 64 + m * 16 + g * 4 + r;
        int col = bn * 128 + wc * 64 + n * 16 + c;
        float v = acc[m][n][r];
        if (EPI == 0){
          int t = row >> 3, b = row & 7, hh = col >> 6, dd = col & 63;
          ((u16*)Cv)[(((size_t)(b * H_ + hh)) * T_ + t) * HD_ + dd] = f2bf(v);
        } else {
          ((float*)Cv)[(size_t)row * N + col] = v + bias[col];
        }
      }
  // ---- fused qsq (EPI==0): thread's 4 n-frags cover all 64 cols of head bn*2+wc
  if (EPI == 0){
    const float QS_SCALE = 0.125f * 1.44269504088896340736f;
    int head = bn * 2 + wc;
    #pragma unroll
    for (int m = 0; m < 4; ++m)
      #pragma unroll
      for (int r = 0; r < 4; ++r){
        float ss = 0.f;
        #pragma unroll
        for (int n = 0; n < 4; ++n){
          float f = bf2f(f2bf(acc[m][n][r]));   // same rounding as stored qb
          ss = fmaf(f, f, ss);
        }
        ss += __shfl_xor(ss, 1);
        ss += __shfl_xor(ss, 2);
        ss += __shfl_xor(ss, 4);
        ss += __shfl_xor(ss, 8);
        if (c == 0){
          int row = bm * 128 + wr * 64 + m * 16 + g * 4 + r;
          int t = row >> 3, b = row & 7;
          qsq[(size_t)(b * H_ + head) * T_ + t] = ss * QS_SCALE;
        }
      }
  }
}

// ---------------- u^T = B_h^T q^T; 4 waves/block, wave w owns one 64-t tile ----------------
__global__ __launch_bounds__(256) void k_u(const u16* __restrict__ qb, const u16* __restrict__ Bt,
                                           u16* __restrict__ ubt){
  int blk = (int)blockIdx.x;            // 512 blocks
  int bh = blk >> 2;
  int w = threadIdx.x >> 6;
  int tt = (blk & 3) * 4 + w;
  int h = bh & 15, t0 = tt * 64;
  int lane = threadIdx.x & 63, g = lane >> 4, c = lane & 15;
  bf16x8 af[4][2], bq[4][2];
  #pragma unroll
  for (int mf = 0; mf < 4; ++mf)
    #pragma unroll
    for (int kk = 0; kk < 2; ++kk)
      af[mf][kk] = *(const bf16x8*)(Bt + ((size_t)(h * 64 + mf * 16 + c)) * 64 + kk * 32 + g * 8);
  #pragma unroll
  for (int nf = 0; nf < 4; ++nf)
    #pragma unroll
    for (int kk = 0; kk < 2; ++kk)
      bq[nf][kk] = *(const bf16x8*)(qb + ((size_t)(bh * 1024 + t0 + nf * 16 + c)) * 64 + kk * 32 + g * 8);
  f32x4 zero = {0.f, 0.f, 0.f, 0.f};
  f32x4 acc[4][4];
  #pragma unroll
  for (int mf = 0; mf < 4; ++mf)
    #pragma unroll
    for (int nf = 0; nf < 4; ++nf) acc[mf][nf] = zero;
  #pragma unroll
  for (int kk = 0; kk < 2; ++kk)
    #pragma unroll
    for (int mf = 0; mf < 4; ++mf)
      #pragma unroll
      for (int nf = 0; nf < 4; ++nf)
        acc[mf][nf] = __builtin_amdgcn_mfma_f32_16x16x32_bf16(af[mf][kk], bq[nf][kk], acc[mf][nf], 0, 0, 0);
  #pragma unroll
  for (int mf = 0; mf < 4; ++mf)
    #pragma unroll
    for (int nf = 0; nf < 4; ++nf)
      #pragma unroll
      for (int r = 0; r < 4; ++r)
        ubt[((size_t)(bh * 64 + mf * 16 + g * 4 + r)) * 1024 + t0 + nf * 16 + c] = f2bf(acc[mf][nf][r]);
}

// ---------------- L2 attention: TBLK=256, 8 waves x 32 t, dbuf gl_lds, m97 schedule ----------------
// (round-16 version, 52.2 us proven) 8 waves share each 64-s K/U tile.
__global__ __launch_bounds__(512, 2) void k_attn(const u16* __restrict__ qb, const u16* __restrict__ ubt,
                                                 const float* __restrict__ qsq, u16* __restrict__ obm){
  int i = (int)blockIdx.x;              // 512 blocks
  // XCD grouping: XCD (i&7) owns bh in [16*(i&7), ...+16), 4 t-tiles each.
  int bh = ((i & 7) << 4) + (i >> 5);
  int tt = (i >> 3) & 3;
  int b = bh >> 4, h = bh & 15;
  int tid = threadIdx.x, w = tid >> 6, lane = tid & 63;
  int lo = lane & 31, hi = lane >> 5;
  __shared__ u16 Kl[2][64 * 64];
  __shared__ u16 Ul[2][64 * 64];
  __shared__ float Qs[1024];
  const float C1 = 0.25f * 1.44269504088896340736f;
  int t0 = tt * 256 + w * 32;
  const u16* qbh = qb + (size_t)bh * 65536;    // [t][64]
  const u16* ubh = ubt + (size_t)bh * 65536;   // [e][1024]
  const float* qsb = qsq + (size_t)bh * 1024;
  // stage the whole scaled-qsq panel once (4KB, 512 thr x 2 floats)
  *(f32x2*)&Qs[tid * 2] = *(const f32x2*)(qsb + tid * 2);
  // Q B-fragment (col=t=lo, k=d): 4 K=16 slices
  bf16x8 qB[4];
  #pragma unroll
  for (int kd = 0; kd < 4; ++kd)
    qB[kd] = *(const bf16x8*)(qbh + (t0 + lo) * 64 + kd * 16 + hi * 8);
  f32x16 o0 = {0,0,0,0,0,0,0,0,0,0,0,0,0,0,0,0};
  f32x16 o1 = {0,0,0,0,0,0,0,0,0,0,0,0,0,0,0,0};
  const f32x16 zero16 = {0,0,0,0,0,0,0,0,0,0,0,0,0,0,0,0};
  float l_c = 0.f;
  // gload slot: one call per operand per wave; slot = tid -> row=tid>>3, c8=tid&7
  int r0 = tid >> 3, sc0 = ((tid & 7) ^ (r0 & 7)) * 8;   // pre-swizzled source chunk
  int d0 = w * 512;                                      // wave-uniform dest base (u16)
  // prologue: issue tile-0 loads into buf 0
  gl_lds16(qbh + r0 * 64 + sc0, &Kl[0][d0]);
  gl_lds16(ubh + (size_t)r0 * 1024 + sc0, &Ul[0][d0]);
  int cur = 0;
  for (int st = 0; st < 16; ++st){
    int s0 = st * 64;
    __syncthreads();   // drains vmcnt(0): buf[cur] landed; all waves past buf[cur^1] reads
    if (st < 15){
      int s1 = s0 + 64;
      int nb = cur ^ 1;
      gl_lds16(qbh + (s1 + r0) * 64 + sc0, &Kl[nb][d0]);
      gl_lds16(ubh + (size_t)r0 * 1024 + s1 + sc0, &Ul[nb][d0]);
    }
    const u16* Kc = &Kl[cur][0];
    const u16* Uc = &Ul[cur][0];
    #pragma unroll
    for (int ts = 0; ts < 2; ++ts){
      f32x16 sf = zero16;
      __builtin_amdgcn_s_setprio(1);
      #pragma unroll
      for (int kd = 0; kd < 4; ++kd){
        bf16x8 kA = *(const bf16x8*)&Kc[swz(ts * 32 + lo, kd * 32 + hi * 16)];
        sf = __builtin_amdgcn_mfma_f32_32x32x16_bf16(kA, qB[kd], sf, 0, 0, 0);
      }
      __builtin_amdgcn_s_setprio(0);
      f32x4 qs_[4];
      #pragma unroll
      for (int q = 0; q < 4; ++q)
        qs_[q] = *(const f32x4*)&Qs[s0 + ts * 32 + q * 8 + hi * 4];
      float p[16];
      #pragma unroll
      for (int r = 0; r < 16; ++r)
        p[r] = exp2_raw(fmaf(sf[r], C1, -qs_[r >> 2][r & 3]));
      float sA = ((p[0] + p[1]) + (p[2] + p[3])) + ((p[4] + p[5]) + (p[6] + p[7]));
      float sB = ((p[8] + p[9]) + (p[10] + p[11])) + ((p[12] + p[13]) + (p[14] + p[15]));
      l_c += sA + sB;
      u32 W[8];
      #pragma unroll
      for (int q = 0; q < 8; ++q)
        W[q] = ((u32)f2bf_fast(p[2 * q + 1]) << 16) | (u32)f2bf_fast(p[2 * q]);
      // PV for this ts: k-slices m_g = ts*2 + {0,1}
      #pragma unroll
      for (int ml = 0; ml < 2; ++ml){
        int m_g = ts * 2 + ml;
        int base = ml * 4;
        i32x2 sw0 = __builtin_amdgcn_permlane32_swap((int)W[base + 0], (int)W[base + 2], false, false);
        i32x2 sw1 = __builtin_amdgcn_permlane32_swap((int)W[base + 1], (int)W[base + 3], false, false);
        union { u32 wd[4]; bf16x8 v; } pa;
        pa.wd[0] = (u32)sw0[0]; pa.wd[1] = (u32)sw1[0]; pa.wd[2] = (u32)sw0[1]; pa.wd[3] = (u32)sw1[1];
        bf16x8 u0 = *(const bf16x8*)&Uc[swz(lo, m_g * 32 + hi * 16)];
        bf16x8 u1 = *(const bf16x8*)&Uc[swz(32 + lo, m_g * 32 + hi * 16)];
        __builtin_amdgcn_s_setprio(1);
        o0 = __builtin_amdgcn_mfma_f32_32x32x16_bf16(pa.v, u0, o0, 0, 0, 0);
        o1 = __builtin_amdgcn_mfma_f32_32x32x16_bf16(pa.v, u1, o1, 0, 0, 0);
        __builtin_amdgcn_s_setprio(0);
      }
    }
    cur ^= 1;
  }
  // l: combine the two hi-halves; lane j then holds l for t = j&31
  l_c += __shfl_xor(l_c, 32);
  float inv = 1.0f / l_c;
  #pragma unroll
  for (int r = 0; r < 16; ++r){
    int tr = (r & 3) + 8 * (r >> 2) + 4 * hi;
    float invr = __shfl(inv, tr);
    size_t rowb = ((size_t)((t0 + tr) * 8 + b)) * 1024 + h * 64;
    obm[rowb + lo] = f2bf(o0[r] * invr);
    obm[rowb + 32 + lo] = f2bf(o1[r] * invr);
  }
}

extern "C" void kernel_launch(void* const* d_in, const int* in_sizes, int n_in,
                              void* d_out, int out_size, void* d_ws, size_t ws_size,
                              hipStream_t stream) {
  const float* x   = (const float*)d_in[0];
  const float* qw  = (const float*)d_in[1];
  const float* vw  = (const float*)d_in[2];
  const float* ow  = (const float*)d_in[3];
  const float* ob_bias = (const float*)d_in[4];
  float* out = (float*)d_out;

  // d_out (32 MiB) doubles as scratch for qb + ubt only (both dead before GEMM2
  // writes `out`). Bp lives in ws (GEMM1-tail bred must not race qb scatter).
  u16* qb  = (u16*)d_out;                                     // [bh][t][d]  16 MiB
  u16* ubt = (u16*)((char*)d_out + (size_t)16 * 1024 * 1024); // [bh][d][t]  16 MiB

  char* ws = (char*)d_ws;
  size_t off = 0;
  auto alloc = [&](size_t bytes) -> void* {
    void* p = ws + off;
    off += (bytes + 255) & ~(size_t)255;
    return p;
  };
  u16*   wqt = (u16*)  alloc((size_t)1024 * 1024 * 2);   // Wq^T bf16 [n][m]   2 MiB
  u16*   obm = (u16*)  alloc((size_t)8192 * 1024 * 2);   // attn out bf16     16 MiB
  float* qsq = (float*)alloc((size_t)128 * 1024 * 4);    // scaled |q|^2     0.5 MiB
  u16*   Bt  = (u16*)  alloc((size_t)16 * 64 * 64 * 2);  // B_h^T bf16      0.125 MiB
  float* Bp  = (float*)alloc((size_t)16 * 65536 * 4);    // bmat partials      4 MiB

  k_pre<<<512, 256, 0, stream>>>(qw, vw, Bp, qw, wqt);
  // GEMM1 (528 blocks): 512 do q = x @ Wq -> qb scatter + fused qsq; 16 tail reduce Bp -> Bt
  k_gemm<1, 0, 0><<<528, 256, 0, stream>>>(x, wqt, qb, nullptr, 8192, 1024, 1024, Bp, Bt, qsq);
  k_u<<<512, 256, 0, stream>>>(qb, Bt, ubt);
  k_attn<<<512, 512, 0, stream>>>(qb, ubt, qsq, obm);
  // GEMM2: out = obm @ out_w^T + b
  k_gemm<0, 1, 1><<<512, 256, 0, stream>>>(obm, ow, out, ob_bias, 8192, 1024, 1024, nullptr, nullptr, nullptr);
}

// Round 21
// 121.136 us; speedup vs baseline: 1.0293x; 1.0293x over previous
//
#include <hip/hip_runtime.h>
#include <hip/hip_bf16.h>

#define T_ 1024
#define N_ 8
#define D_ 1024
#define H_ 16
#define HD_ 64

typedef __attribute__((ext_vector_type(8))) short bf16x8;
typedef __attribute__((ext_vector_type(2))) float f32x2;
typedef __attribute__((ext_vector_type(4))) float f32x4;
typedef __attribute__((ext_vector_type(16))) float f32x16;
typedef __attribute__((ext_vector_type(4))) int i32x4;
typedef __attribute__((ext_vector_type(2))) int i32x2;
typedef unsigned short u16;
typedef unsigned int u32;

__device__ __forceinline__ float bf2f(u16 u){
  union { float f; unsigned int i; } v; v.i = ((unsigned int)u) << 16; return v.f;
}
__device__ __forceinline__ u16 f2bf(float f){
  union { float f; unsigned int i; } v; v.f = f;
  unsigned int r = v.i + 0x7FFFu + ((v.i >> 16) & 1u);
  return (u16)(r >> 16);
}
__device__ __forceinline__ u16 f2bf_fast(float f){
  __hip_bfloat16 h = __float2bfloat16(f);   // RNE; compiler packs pairs into v_cvt_pk_bf16_f32
  return *reinterpret_cast<u16*>(&h);
}
// raw v_exp_f32: args are well inside normal range (p<=e^15), skip libm fixup tail
__device__ __forceinline__ float exp2_raw(float x){
  float r;
  asm("v_exp_f32 %0, %1" : "=v"(r) : "v"(x));
  return r;
}
// async global->LDS, 16B per lane, dest = wave-uniform base + lane*16
__device__ __forceinline__ void gl_lds16(const u16* g, u16* l){
  __builtin_amdgcn_global_load_lds(
      (const __attribute__((address_space(1))) unsigned int*)g,
      (__attribute__((address_space(3))) unsigned int*)(unsigned int)(unsigned long long)l,
      16, 0, 0);
}

// ---------------- fused pre-kernel: blocks 0-127 = bmatp; 128-383 = wqt ----------------
__global__ __launch_bounds__(256) void k_pre(const float* __restrict__ qw, const float* __restrict__ vw,
                                             float* __restrict__ Bp, const float* __restrict__ Wq,
                                             u16* __restrict__ Wqt){
  __shared__ u16 Qt[64 * 72];
  __shared__ u16 Vt[64 * 72];
  __shared__ float tld[64][65];
  int blk = (int)blockIdx.x;
  int tid = threadIdx.x;
  if (blk < 128){
    int h = blk >> 3, sp = blk & 7;
    int lane = tid & 63, w = tid >> 6;
    int g = lane >> 4, c = lane & 15;
    f32x4 zero = {0.f, 0.f, 0.f, 0.f};
    f32x4 acc[4];
    #pragma unroll
    for (int eb = 0; eb < 4; ++eb) acc[eb] = zero;
    int m = tid >> 2, cg = tid & 3;
    for (int mt = sp * 128; mt < sp * 128 + 128; mt += 64){
      __syncthreads();
      #pragma unroll
      for (int q = 0; q < 4; ++q){
        int e0 = cg * 16 + q * 4;
        f32x4 vq = *(const f32x4*)(qw + (size_t)(mt + m) * D_ + h * 64 + e0);
        f32x4 vv = *(const f32x4*)(vw + (size_t)(mt + m) * D_ + h * 64 + e0);
        #pragma unroll
        for (int j = 0; j < 4; ++j){
          Qt[(e0 + j) * 72 + m] = f2bf_fast(vq[j]);
          Vt[(e0 + j) * 72 + m] = f2bf_fast(vv[j]);
        }
      }
      __syncthreads();
      #pragma unroll
      for (int kk = 0; kk < 2; ++kk){
        bf16x8 av = *(const bf16x8*)&Vt[(w * 16 + c) * 72 + kk * 32 + g * 8];
        #pragma unroll
        for (int eb = 0; eb < 4; ++eb){
          bf16x8 bq = *(const bf16x8*)&Qt[(eb * 16 + c) * 72 + kk * 32 + g * 8];
          acc[eb] = __builtin_amdgcn_mfma_f32_16x16x32_bf16(av, bq, acc[eb], 0, 0, 0);
        }
      }
    }
    #pragma unroll
    for (int eb = 0; eb < 4; ++eb)
      #pragma unroll
      for (int r = 0; r < 4; ++r){
        int d = w * 16 + g * 4 + r, e = eb * 16 + c;
        Bp[(((size_t)sp * 16 + h) * 64 + d) * 64 + e] = acc[eb][r];
      }
  } else {
    int b2 = blk - 128;
    int m0 = (b2 & 15) * 64, n0 = (b2 >> 4) * 64;
    int col = tid & 63, rq = tid >> 6;
    #pragma unroll
    for (int p = 0; p < 16; ++p){
      int row = rq * 16 + p;
      tld[row][col] = Wq[(size_t)(m0 + row) * D_ + n0 + col];
    }
    __syncthreads();
    #pragma unroll
    for (int p = 0; p < 16; ++p){
      int row = rq * 16 + p;
      Wqt[(size_t)(n0 + row) * D_ + m0 + col] = f2bf(tld[col][row]);
    }
  }
}

// swizzled u16-index within a [rows][64] u16 LDS tile: XOR byte-bits 4-6 with row&7
__device__ __forceinline__ int swz(int row, int colbyte){
  return row * 64 + (((colbyte) ^ ((row & 7) << 4)) >> 1);
}

// ---------------- 128x128 bf16 MFMA GEMM, A[MxK] @ B^T (B given [N][K]) ----------------
// Double-buffered; bf16 operand via global_load_lds (linear dest, pre-swizzled src);
// f32 operand via T14 split (reg loads early, ds_write after compute).
// EPI=0: scatter to qb bf16 + tail blocks (>=512) reduce Bp (ws) -> Bt (ws).
// EPI=1: C f32 + bias.
template<int A_F32, int B_F32, int EPI>
__global__ __launch_bounds__(256) void k_gemm(const void* __restrict__ A_, const void* __restrict__ B_,
                                              void* __restrict__ Cv, const float* __restrict__ bias,
                                              int M, int N, int K,
                                              const float* __restrict__ Bp, u16* __restrict__ Bt){
  int ii = (int)blockIdx.x;
  if (EPI == 0 && ii >= 512){
    // ---- fused bred: 16 blocks x 256 thr x 16 elems = 65536 (Bp/Bt both in ws)
    int base = (ii - 512) * 4096 + threadIdx.x * 16;
    #pragma unroll 4
    for (int e = 0; e < 16; ++e){
      int idx = base + e;
      float s = 0.f;
      #pragma unroll
      for (int j = 0; j < 8; ++j) s += Bp[(size_t)j * 65536 + idx];
      Bt[idx] = f2bf(s * 0.125f);
    }
    return;
  }
  int nbn = N >> 7;
  int sw = (ii & 7) * 64 + (ii >> 3);      // XCD-contiguous chunks (512 = 8*64 blocks)
  int bm = sw / nbn, bn = sw % nbn;
  int tid = threadIdx.x, lane = tid & 63, wid = tid >> 6;
  int wr = wid >> 1, wc = wid & 1, g = lane >> 4, c = lane & 15;
  __shared__ u16 As[2][128 * 64];
  __shared__ u16 Bs[2][128 * 64];
  int srow[4], scol[4], sdst[4];
  #pragma unroll
  for (int p = 0; p < 4; ++p){
    int slot = (wid * 4 + p) * 64 + lane;
    int row = slot >> 3, c8 = slot & 7;
    srow[p] = row;
    scol[p] = (c8 ^ (row & 7)) * 8;   // pre-swizzled source chunk
    sdst[p] = slot * 8;               // linear dest
  }
  int rrow[4], rc8[4];
  #pragma unroll
  for (int p = 0; p < 4; ++p){
    int ci = tid + p * 256;
    rrow[p] = ci >> 3; rc8[p] = ci & 7;
  }
  f32x4 zero = {0.f, 0.f, 0.f, 0.f};
  f32x4 acc[4][4];
  #pragma unroll
  for (int m = 0; m < 4; ++m)
    #pragma unroll
    for (int n = 0; n < 4; ++n) acc[m][n] = zero;
  f32x4 rA[4][2], rB[4][2];
  const u16* Ab = (const u16*)A_;
  const u16* Bb = (const u16*)B_;
  const float* Af = (const float*)A_;
  const float* Bf = (const float*)B_;
  // ---- prologue: stage tile 0 into buf 0
  if (!A_F32){
    #pragma unroll
    for (int p = 0; p < 4; ++p)
      gl_lds16(Ab + (size_t)(bm * 128 + srow[p]) * K + scol[p], &As[0][sdst[p]]);
  }
  if (!B_F32){
    #pragma unroll
    for (int p = 0; p < 4; ++p)
      gl_lds16(Bb + (size_t)(bn * 128 + srow[p]) * K + scol[p], &Bs[0][sdst[p]]);
  }
  if (A_F32){
    #pragma unroll
    for (int p = 0; p < 4; ++p){
      const float* src = Af + (size_t)(bm * 128 + rrow[p]) * K + rc8[p] * 8;
      rA[p][0] = *(const f32x4*)src;
      rA[p][1] = *(const f32x4*)(src + 4);
    }
    #pragma unroll
    for (int p = 0; p < 4; ++p){
      union { u16 u[8]; i32x4 v; } pk;
      #pragma unroll
      for (int j = 0; j < 4; ++j){ pk.u[j] = f2bf_fast(rA[p][0][j]); pk.u[4 + j] = f2bf_fast(rA[p][1][j]); }
      *(i32x4*)&As[0][swz(rrow[p], rc8[p] * 16)] = pk.v;
    }
  }
  if (B_F32){
    #pragma unroll
    for (int p = 0; p < 4; ++p){
      const float* src = Bf + (size_t)(bn * 128 + rrow[p]) * K + rc8[p] * 8;
      rB[p][0] = *(const f32x4*)src;
      rB[p][1] = *(const f32x4*)(src + 4);
    }
    #pragma unroll
    for (int p = 0; p < 4; ++p){
      union { u16 u[8]; i32x4 v; } pk;
      #pragma unroll
      for (int j = 0; j < 4; ++j){ pk.u[j] = f2bf_fast(rB[p][0][j]); pk.u[4 + j] = f2bf_fast(rB[p][1][j]); }
      *(i32x4*)&Bs[0][swz(rrow[p], rc8[p] * 16)] = pk.v;
    }
  }
  int NT = K >> 6;
  int cur = 0;
  for (int st = 0; st < NT; ++st){
    __syncthreads();   // buf[cur] ready; prev reads of buf[cur^1] done
    int kt1 = (st + 1) * 64;
    int nb = cur ^ 1;
    if (st + 1 < NT){
      if (!A_F32){
        #pragma unroll
        for (int p = 0; p < 4; ++p)
          gl_lds16(Ab + (size_t)(bm * 128 + srow[p]) * K + kt1 + scol[p], &As[nb][sdst[p]]);
      }
      if (!B_F32){
        #pragma unroll
        for (int p = 0; p < 4; ++p)
          gl_lds16(Bb + (size_t)(bn * 128 + srow[p]) * K + kt1 + scol[p], &Bs[nb][sdst[p]]);
      }
      if (A_F32){
        #pragma unroll
        for (int p = 0; p < 4; ++p){
          const float* src = Af + (size_t)(bm * 128 + rrow[p]) * K + kt1 + rc8[p] * 8;
          rA[p][0] = *(const f32x4*)src;
          rA[p][1] = *(const f32x4*)(src + 4);
        }
      }
      if (B_F32){
        #pragma unroll
        for (int p = 0; p < 4; ++p){
          const float* src = Bf + (size_t)(bn * 128 + rrow[p]) * K + kt1 + rc8[p] * 8;
          rB[p][0] = *(const f32x4*)src;
          rB[p][1] = *(const f32x4*)(src + 4);
        }
      }
    }
    // ---- compute on buf[cur]
    #pragma unroll
    for (int kk = 0; kk < 2; ++kk){
      bf16x8 af[4], bfr[4];
      #pragma unroll
      for (int m = 0; m < 4; ++m){
        int row = wr * 64 + m * 16 + c;
        af[m] = *(const bf16x8*)&As[cur][swz(row, kk * 64 + g * 16)];
      }
      #pragma unroll
      for (int n = 0; n < 4; ++n){
        int row = wc * 64 + n * 16 + c;
        bfr[n] = *(const bf16x8*)&Bs[cur][swz(row, kk * 64 + g * 16)];
      }
      #pragma unroll
      for (int m = 0; m < 4; ++m)
        #pragma unroll
        for (int n = 0; n < 4; ++n)
          acc[m][n] = __builtin_amdgcn_mfma_f32_16x16x32_bf16(af[m], bfr[n], acc[m][n], 0, 0, 0);
    }
    // ---- late ds_write of the f32-path tile
    if (st + 1 < NT){
      if (A_F32){
        #pragma unroll
        for (int p = 0; p < 4; ++p){
          union { u16 u[8]; i32x4 v; } pk;
          #pragma unroll
          for (int j = 0; j < 4; ++j){ pk.u[j] = f2bf_fast(rA[p][0][j]); pk.u[4 + j] = f2bf_fast(rA[p][1][j]); }
          *(i32x4*)&As[nb][swz(rrow[p], rc8[p] * 16)] = pk.v;
        }
      }
      if (B_F32){
        #pragma unroll
        for (int p = 0; p < 4; ++p){
          union { u16 u[8]; i32x4 v; } pk;
          #pragma unroll
          for (int j = 0; j < 4; ++j){ pk.u[j] = f2bf_fast(rB[p][0][j]); pk.u[4 + j] = f2bf_fast(rB[p][1][j]); }
          *(i32x4*)&Bs[nb][swz(rrow[p], rc8[p] * 16)] = pk.v;
        }
      }
    }
    cur ^= 1;
  }
  #pragma unroll
  for (int m = 0; m < 4; ++m)
    #pragma unroll
    for (int n = 0; n < 4; ++n)
      #pragma unroll
      for (int r = 0; r < 4; ++r){
        int row = bm * 128 + wr * 64 + m * 16 + g * 4 + r;
        int col = bn * 128 + wc * 64 + n * 16 + c;
        float v = acc[m][n][r];
        if (EPI == 0){
          int t = row >> 3, b = row & 7, hh = col >> 6, dd = col & 63;
          ((u16*)Cv)[(((size_t)(b * H_ + hh)) * T_ + t) * HD_ + dd] = f2bf(v);
        } else {
          ((float*)Cv)[(size_t)row * N + col] = v + bias[col];
        }
      }
}

// ---------------- u^T = B_h^T q^T; 4 waves/block, wave w owns one 64-t tile ----------------
__global__ __launch_bounds__(256) void k_u(const u16* __restrict__ qb, const u16* __restrict__ Bt,
                                           u16* __restrict__ ubt, float* __restrict__ qsq){
  int blk = (int)blockIdx.x;            // 512 blocks
  int bh = blk >> 2;
  int w = threadIdx.x >> 6;
  int tt = (blk & 3) * 4 + w;
  int h = bh & 15, t0 = tt * 64;
  int lane = threadIdx.x & 63, g = lane >> 4, c = lane & 15;
  const float QS_SCALE = 0.125f * 1.44269504088896340736f;
  bf16x8 af[4][2], bq[4][2];
  #pragma unroll
  for (int mf = 0; mf < 4; ++mf)
    #pragma unroll
    for (int kk = 0; kk < 2; ++kk)
      af[mf][kk] = *(const bf16x8*)(Bt + ((size_t)(h * 64 + mf * 16 + c)) * 64 + kk * 32 + g * 8);
  #pragma unroll
  for (int nf = 0; nf < 4; ++nf)
    #pragma unroll
    for (int kk = 0; kk < 2; ++kk)
      bq[nf][kk] = *(const bf16x8*)(qb + ((size_t)(bh * 1024 + t0 + nf * 16 + c)) * 64 + kk * 32 + g * 8);
  // q_sq from the same bf16 q; prescaled by 0.125*log2(e)
  #pragma unroll
  for (int nf = 0; nf < 4; ++nf){
    float ss = 0.f;
    #pragma unroll
    for (int kk = 0; kk < 2; ++kk)
      #pragma unroll
      for (int j = 0; j < 8; ++j){ float f = bf2f((u16)bq[nf][kk][j]); ss = fmaf(f, f, ss); }
    ss += __shfl_xor(ss, 16);
    ss += __shfl_xor(ss, 32);
    if (lane < 16) qsq[(size_t)bh * 1024 + t0 + nf * 16 + lane] = ss * QS_SCALE;
  }
  f32x4 zero = {0.f, 0.f, 0.f, 0.f};
  f32x4 acc[4][4];
  #pragma unroll
  for (int mf = 0; mf < 4; ++mf)
    #pragma unroll
    for (int nf = 0; nf < 4; ++nf) acc[mf][nf] = zero;
  #pragma unroll
  for (int kk = 0; kk < 2; ++kk)
    #pragma unroll
    for (int mf = 0; mf < 4; ++mf)
      #pragma unroll
      for (int nf = 0; nf < 4; ++nf)
        acc[mf][nf] = __builtin_amdgcn_mfma_f32_16x16x32_bf16(af[mf][kk], bq[nf][kk], acc[mf][nf], 0, 0, 0);
  #pragma unroll
  for (int mf = 0; mf < 4; ++mf)
    #pragma unroll
    for (int nf = 0; nf < 4; ++nf)
      #pragma unroll
      for (int r = 0; r < 4; ++r)
        ubt[((size_t)(bh * 64 + mf * 16 + g * 4 + r)) * 1024 + t0 + nf * 16 + c] = f2bf(acc[mf][nf][r]);
}

// ---------------- L2 attention: TBLK=256, 8 waves x 32 t, dbuf gl_lds, m97 schedule ----------------
// (round-16 version, 52.2 us proven) 8 waves share each 64-s K/U tile.
__global__ __launch_bounds__(512, 2) void k_attn(const u16* __restrict__ qb, const u16* __restrict__ ubt,
                                                 const float* __restrict__ qsq, u16* __restrict__ obm){
  int i = (int)blockIdx.x;              // 512 blocks
  // XCD grouping: XCD (i&7) owns bh in [16*(i&7), ...+16), 4 t-tiles each.
  int bh = ((i & 7) << 4) + (i >> 5);
  int tt = (i >> 3) & 3;
  int b = bh >> 4, h = bh & 15;
  int tid = threadIdx.x, w = tid >> 6, lane = tid & 63;
  int lo = lane & 31, hi = lane >> 5;
  __shared__ u16 Kl[2][64 * 64];
  __shared__ u16 Ul[2][64 * 64];
  __shared__ float Qs[1024];
  const float C1 = 0.25f * 1.44269504088896340736f;
  int t0 = tt * 256 + w * 32;
  const u16* qbh = qb + (size_t)bh * 65536;    // [t][64]
  const u16* ubh = ubt + (size_t)bh * 65536;   // [e][1024]
  const float* qsb = qsq + (size_t)bh * 1024;
  // stage the whole scaled-qsq panel once (4KB, 512 thr x 2 floats)
  *(f32x2*)&Qs[tid * 2] = *(const f32x2*)(qsb + tid * 2);
  // Q B-fragment (col=t=lo, k=d): 4 K=16 slices
  bf16x8 qB[4];
  #pragma unroll
  for (int kd = 0; kd < 4; ++kd)
    qB[kd] = *(const bf16x8*)(qbh + (t0 + lo) * 64 + kd * 16 + hi * 8);
  f32x16 o0 = {0,0,0,0,0,0,0,0,0,0,0,0,0,0,0,0};
  f32x16 o1 = {0,0,0,0,0,0,0,0,0,0,0,0,0,0,0,0};
  const f32x16 zero16 = {0,0,0,0,0,0,0,0,0,0,0,0,0,0,0,0};
  float l_c = 0.f;
  // gload slot: one call per operand per wave; slot = tid -> row=tid>>3, c8=tid&7
  int r0 = tid >> 3, sc0 = ((tid & 7) ^ (r0 & 7)) * 8;   // pre-swizzled source chunk
  int d0 = w * 512;                                      // wave-uniform dest base (u16)
  // prologue: issue tile-0 loads into buf 0
  gl_lds16(qbh + r0 * 64 + sc0, &Kl[0][d0]);
  gl_lds16(ubh + (size_t)r0 * 1024 + sc0, &Ul[0][d0]);
  int cur = 0;
  for (int st = 0; st < 16; ++st){
    int s0 = st * 64;
    __syncthreads();   // drains vmcnt(0): buf[cur] landed; all waves past buf[cur^1] reads
    if (st < 15){
      int s1 = s0 + 64;
      int nb = cur ^ 1;
      gl_lds16(qbh + (s1 + r0) * 64 + sc0, &Kl[nb][d0]);
      gl_lds16(ubh + (size_t)r0 * 1024 + s1 + sc0, &Ul[nb][d0]);
    }
    const u16* Kc = &Kl[cur][0];
    const u16* Uc = &Ul[cur][0];
    #pragma unroll
    for (int ts = 0; ts < 2; ++ts){
      f32x16 sf = zero16;
      __builtin_amdgcn_s_setprio(1);
      #pragma unroll
      for (int kd = 0; kd < 4; ++kd){
        bf16x8 kA = *(const bf16x8*)&Kc[swz(ts * 32 + lo, kd * 32 + hi * 16)];
        sf = __builtin_amdgcn_mfma_f32_32x32x16_bf16(kA, qB[kd], sf, 0, 0, 0);
      }
      __builtin_amdgcn_s_setprio(0);
      f32x4 qs_[4];
      #pragma unroll
      for (int q = 0; q < 4; ++q)
        qs_[q] = *(const f32x4*)&Qs[s0 + ts * 32 + q * 8 + hi * 4];
      float p[16];
      #pragma unroll
      for (int r = 0; r < 16; ++r)
        p[r] = exp2_raw(fmaf(sf[r], C1, -qs_[r >> 2][r & 3]));
      float sA = ((p[0] + p[1]) + (p[2] + p[3])) + ((p[4] + p[5]) + (p[6] + p[7]));
      float sB = ((p[8] + p[9]) + (p[10] + p[11])) + ((p[12] + p[13]) + (p[14] + p[15]));
      l_c += sA + sB;
      u32 W[8];
      #pragma unroll
      for (int q = 0; q < 8; ++q)
        W[q] = ((u32)f2bf_fast(p[2 * q + 1]) << 16) | (u32)f2bf_fast(p[2 * q]);
      // PV for this ts: k-slices m_g = ts*2 + {0,1}
      #pragma unroll
      for (int ml = 0; ml < 2; ++ml){
        int m_g = ts * 2 + ml;
        int base = ml * 4;
        i32x2 sw0 = __builtin_amdgcn_permlane32_swap((int)W[base + 0], (int)W[base + 2], false, false);
        i32x2 sw1 = __builtin_amdgcn_permlane32_swap((int)W[base + 1], (int)W[base + 3], false, false);
        union { u32 wd[4]; bf16x8 v; } pa;
        pa.wd[0] = (u32)sw0[0]; pa.wd[1] = (u32)sw1[0]; pa.wd[2] = (u32)sw0[1]; pa.wd[3] = (u32)sw1[1];
        bf16x8 u0 = *(const bf16x8*)&Uc[swz(lo, m_g * 32 + hi * 16)];
        bf16x8 u1 = *(const bf16x8*)&Uc[swz(32 + lo, m_g * 32 + hi * 16)];
        __builtin_amdgcn_s_setprio(1);
        o0 = __builtin_amdgcn_mfma_f32_32x32x16_bf16(pa.v, u0, o0, 0, 0, 0);
        o1 = __builtin_amdgcn_mfma_f32_32x32x16_bf16(pa.v, u1, o1, 0, 0, 0);
        __builtin_amdgcn_s_setprio(0);
      }
    }
    cur ^= 1;
  }
  // l: combine the two hi-halves; lane j then holds l for t = j&31
  l_c += __shfl_xor(l_c, 32);
  float inv = 1.0f / l_c;
  #pragma unroll
  for (int r = 0; r < 16; ++r){
    int tr = (r & 3) + 8 * (r >> 2) + 4 * hi;
    float invr = __shfl(inv, tr);
    size_t rowb = ((size_t)((t0 + tr) * 8 + b)) * 1024 + h * 64;
    obm[rowb + lo] = f2bf(o0[r] * invr);
    obm[rowb + 32 + lo] = f2bf(o1[r] * invr);
  }
}

extern "C" void kernel_launch(void* const* d_in, const int* in_sizes, int n_in,
                              void* d_out, int out_size, void* d_ws, size_t ws_size,
                              hipStream_t stream) {
  const float* x   = (const float*)d_in[0];
  const float* qw  = (const float*)d_in[1];
  const float* vw  = (const float*)d_in[2];
  const float* ow  = (const float*)d_in[3];
  const float* ob_bias = (const float*)d_in[4];
  float* out = (float*)d_out;

  // d_out (32 MiB) doubles as scratch for qb + ubt only (both dead before GEMM2
  // writes `out`). Bp lives in ws (GEMM1-tail bred must not race qb scatter).
  u16* qb  = (u16*)d_out;                                     // [bh][t][d]  16 MiB
  u16* ubt = (u16*)((char*)d_out + (size_t)16 * 1024 * 1024); // [bh][d][t]  16 MiB

  char* ws = (char*)d_ws;
  size_t off = 0;
  auto alloc = [&](size_t bytes) -> void* {
    void* p = ws + off;
    off += (bytes + 255) & ~(size_t)255;
    return p;
  };
  u16*   wqt = (u16*)  alloc((size_t)1024 * 1024 * 2);   // Wq^T bf16 [n][m]   2 MiB
  u16*   obm = (u16*)  alloc((size_t)8192 * 1024 * 2);   // attn out bf16     16 MiB
  float* qsq = (float*)alloc((size_t)128 * 1024 * 4);    // scaled |q|^2     0.5 MiB
  u16*   Bt  = (u16*)  alloc((size_t)16 * 64 * 64 * 2);  // B_h^T bf16      0.125 MiB
  float* Bp  = (float*)alloc((size_t)8 * 65536 * 4);     // bmat partials      2 MiB

  k_pre<<<384, 256, 0, stream>>>(qw, vw, Bp, qw, wqt);
  // GEMM1 (528 blocks): 512 do q = x @ Wq -> qb scatter; 16 tail blocks reduce Bp -> Bt
  k_gemm<1, 0, 0><<<528, 256, 0, stream>>>(x, wqt, qb, nullptr, 8192, 1024, 1024, Bp, Bt);
  k_u<<<512, 256, 0, stream>>>(qb, Bt, ubt, qsq);
  k_attn<<<512, 512, 0, stream>>>(qb, ubt, qsq, obm);
  // GEMM2: out = obm @ out_w^T + b
  k_gemm<0, 1, 1><<<512, 256, 0, stream>>>(obm, ow, out, ob_bias, 8192, 1024, 1024, nullptr, nullptr);
}